// Round 6
// baseline (118.472 us; speedup 1.0000x reference)
//
#include <hip/hip_runtime.h>
#include <math.h>

// ---------------------------------------------------------------------------
// HyperbolicInfoNCE on MI355X — Round 12: col sums via LDS (ds_add_f32),
// global atomics only at kernel end; stride-168 experiment reverted.
//
// R11 post-mortem: SQ_LDS_BANK_CONFLICT identical (2,621,440 = 4cyc x
// 655,360 b128 reads) at stride 320B AND 336B -> layout-independent ->
// it's the inherent multi-phase cost of wave64 ds_read_b128 (~1us/CU,
// never the critical path). Padding regressed (extra fetch/convert work,
// occupancy 31->22). REVERTED to stride 160.
//
// Real per-tile stall (arithmetic): per-wave-tile issue ~2000cyc but
// T_tile ~10900cyc. The ~8.5K gap = in-loop global atomicAdd to colRep +
// __syncthreads' vmcnt(0) drain (waits on atomics!). 16 blocks x 4 waves
// hammer the SAME 64 floats every tile -> contended L2 atomic RTT paid at
// all 8 barriers.
//
// R12: col partials -> LDS colAcc[512] via atomicAdd on __shared__
// (ds_add_f32: lgkmcnt-tracked, no L2, 4-way max contention). ONE batch of
// fire-and-forget global atomics at kernel end (no barrier after). In-loop
// barrier now only drains stage loads (done under compute). Also: convert
// vectorized (8 elem/thread, ushort8 stores); colRep interleaved [col][4]
// so finalize reads dwordx4.
// ---------------------------------------------------------------------------

#define BDIM   8192
#define K_IN   129
#define K_PAD  160      // 5 * 32
#define BK     32
#define NKT    5        // k-tiles of 32
#define CTILES 8        // 64-col tiles per block (128 rows x 512 cols)

typedef __bf16  bf16x8 __attribute__((ext_vector_type(8)));
typedef float   f32x4  __attribute__((ext_vector_type(4)));
typedef unsigned short u16x8 __attribute__((ext_vector_type(8)));

// ws layout (bytes)
#define OFF_A    0u
#define OFF_B    (BDIM * K_PAD * 2u)                  // 2,621,440
#define OFF_RS   (2u * BDIM * K_PAD * 2u)             // 5,242,880
#define OFF_CP   (OFF_RS + BDIM * 4u)                 // col sums, [col][4 reps]
#define OFF_DG   (OFF_CP + 4u * BDIM * 4u)

// ---- hardware transcendentals (v_sqrt_f32 / v_log_f32 / v_exp_f32) ----
__device__ __forceinline__ float fast_sqrt(float x) {
#if __has_builtin(__builtin_amdgcn_sqrtf)
    return __builtin_amdgcn_sqrtf(x);
#else
    return sqrtf(x);
#endif
}
__device__ __forceinline__ float fast_log2(float x) {
#if __has_builtin(__builtin_amdgcn_logf)
    return __builtin_amdgcn_logf(x);       // log base 2
#else
    return __log2f(x);
#endif
}
__device__ __forceinline__ float fast_exp2(float x) {
#if __has_builtin(__builtin_amdgcn_exp2f)
    return __builtin_amdgcn_exp2f(x);      // 2^x
#else
    extern "C" __device__ float __ocml_native_exp2_f32(float);
    return __ocml_native_exp2_f32(x);
#endif
}

__device__ __forceinline__ unsigned short f2bf_rne(float f) {
    unsigned int u = __float_as_uint(f);
    u += 0x7FFFu + ((u >> 16) & 1u);   // round-to-nearest-even
    return (unsigned short)(u >> 16);
}

// ---------------------------------------------------------------------------
// Kernel 1: fp32 -> bf16, vectorized: each thread emits 8 contiguous padded
// shorts of A and of B (ushort8 stores). K zero-padded 129->160, Lorentz
// metric folded into A (negate col 0). Also zeroes row_sum + col sums.
// Grid: BDIM*20 threads (163,840) = 640 blocks.
// ---------------------------------------------------------------------------
__global__ __launch_bounds__(256) void convert_kernel(
    const float* __restrict__ z1, const float* __restrict__ z2,
    unsigned short* __restrict__ A, unsigned short* __restrict__ B,
    float* __restrict__ rs_cp)
{
    int v = blockIdx.x * 256 + threadIdx.x;
    if (v < 5 * BDIM) rs_cp[v] = 0.f;          // rs (8192) + cp (4*8192)
    if (v >= BDIM * (K_PAD / 8)) return;
    int r  = v / (K_PAD / 8);
    int c8 = (v - r * (K_PAD / 8)) * 8;
    u16x8 a, b;
    #pragma unroll
    for (int i = 0; i < 8; ++i) {
        int c = c8 + i;
        float va = 0.f, vb = 0.f;
        if (c < K_IN) {
            va = z1[r * K_IN + c];
            vb = z2[r * K_IN + c];
            if (c == 0) va = -va;              // Lorentz metric on coord 0
        }
        a[i] = f2bf_rne(va);
        b[i] = f2bf_rne(vb);
    }
    *(u16x8*)(A + r * K_PAD + c8) = a;
    *(u16x8*)(B + r * K_PAD + c8) = b;
}

// ---------------------------------------------------------------------------
// Kernel 2: strip-GEMM with fused acosh/exp epilogue; B staged through a
// double-buffered LDS pipeline (global_load_lds); col sums in LDS.
//   grid = 1024: bid = chunk*64 + strip  (consecutive blocks share B-chunk)
//   block: rows [strip*128, +128) x cols [chunk*512, +512)
//   wave w (0..3): rows [strip*128 + w*32, +32), 8 col-tiles of 64
//   fragment layouts (guide-verified, m89/m91):
//     A/B operand: elem [m=lane&15][k=(lane>>4)*8 + j]
//     C/D:         elem [row=(lane>>4)*4 + reg][col=lane&15]
// ---------------------------------------------------------------------------

// Stage one 64-col B-tile (20KB contiguous global chunk) into Bs[bufidx].
// Each wave issues 5 async 1KB copies; LDS dest wave-uniform + lane*16 (m104).
#define STAGE(bufidx, cb)                                                     \
    {                                                                         \
        const char* _gp = (const char*)(B + (size_t)(cb) * K_PAD)             \
                          + wave * 5120 + lane * 16;                          \
        unsigned short* _lp = &Bs[bufidx][wave * 2560];                       \
        _Pragma("unroll")                                                     \
        for (int _i = 0; _i < 5; ++_i)                                        \
            __builtin_amdgcn_global_load_lds(                                 \
                (const __attribute__((address_space(1))) void*)               \
                    (_gp + _i * 1024),                                        \
                (__attribute__((address_space(3))) void*)(_lp + _i * 512),    \
                16, 0, 0);                                                    \
    }

// MFMA + fused epilogue for one 32x64 wave-tile read from Bs[bufidx].
// Col partials go to LDS colAcc (ds_add_f32) — NO global atomics in loop.
#define COMPUTE(bufidx, cb)                                                   \
    {                                                                         \
        const int colBase = (cb);                                             \
        const unsigned short* _Bt = &Bs[bufidx][0];                           \
        f32x4 acc[2][4] = {};                                                 \
        _Pragma("unroll")                                                     \
        for (int kt = 0; kt < NKT; ++kt) {                                    \
            bf16x8 bfr[4];                                                    \
            _Pragma("unroll")                                                 \
            for (int j = 0; j < 4; ++j)                                       \
                bfr[j] = *(const bf16x8*)                                     \
                    &_Bt[(l16 + j * 16) * K_PAD + quad * 8 + kt * BK];        \
            _Pragma("unroll")                                                 \
            for (int i = 0; i < 2; ++i)                                       \
                _Pragma("unroll")                                             \
                for (int j = 0; j < 4; ++j)                                   \
                    acc[i][j] = __builtin_amdgcn_mfma_f32_16x16x32_bf16(      \
                        Ah[i][kt], bfr[j], acc[i][j], 0, 0, 0);               \
        }                                                                     \
        const bool diagTile = (colBase == (rowBase & ~63));                   \
        const int  dj       = (rowBase >> 4) & 2;                             \
        float colp[4] = {0.f, 0.f, 0.f, 0.f};                                 \
        _Pragma("unroll")                                                     \
        for (int i = 0; i < 2; ++i) {                                         \
            _Pragma("unroll")                                                 \
            for (int j = 0; j < 4; ++j) {                                     \
                _Pragma("unroll")                                             \
                for (int reg = 0; reg < 4; ++reg) {                           \
                    float inner = acc[i][j][reg];                             \
                    float x = fmaxf(-inner, 1.000001f);                       \
                    float s = fast_sqrt(__builtin_fmaf(x, x, -1.0f));         \
                    float l2u = fast_log2(x + s);                             \
                    float e = fast_exp2(-14.285714285714286f * l2u);          \
                    rowp[i][reg] += e;                                        \
                    colp[j]      += e;                                        \
                    if (diagTile && (j - i) == dj && (quad * 4 + reg) == l16){\
                        int R = rowBase + i * 16 + quad * 4 + reg;            \
                        diag[R] = -9.902102579427789f * l2u;                  \
                    }                                                         \
                }                                                             \
            }                                                                 \
        }                                                                     \
        _Pragma("unroll")                                                     \
        for (int j = 0; j < 4; ++j) {                                         \
            float v = colp[j];                                                \
            v += __shfl_xor(v, 16);                                           \
            v += __shfl_xor(v, 32);                                           \
            if (quad == 0)                                                    \
                atomicAdd(&colAcc[(colBase - colChunk) + j * 16 + l16], v);   \
        }                                                                     \
    }

__global__ __launch_bounds__(256, 3) void gemm_epilogue_kernel(
    const unsigned short* __restrict__ A, const unsigned short* __restrict__ B,
    float* __restrict__ row_sum, float* __restrict__ col_part,
    float* __restrict__ diag)
{
    const int t    = threadIdx.x;
    const int lane = t & 63;
    const int wave = t >> 6;
    const int quad = lane >> 4;
    const int l16  = lane & 15;

    const int strip = blockIdx.x & 63;
    const int chunk = blockIdx.x >> 6;
    const int rowBase  = strip * 128 + wave * 32;   // wave's first row
    const int colChunk = chunk * 512;               // block's first col

    const unsigned short* Abase = A + (rowBase + l16) * K_PAD + quad * 8;

    // B-tile double buffer (linear copy of contiguous global chunk) + block
    // col accumulator (ds_add_f32 path, drained to global ONCE at end).
    __shared__ __align__(16) unsigned short Bs[2][64 * K_PAD];
    __shared__ float colAcc[512];

    for (int c = t; c < 512; c += 256) colAcc[c] = 0.f;

    // ---- hoist the entire A operand for this wave: 2 row-frags x 5 k-tiles
    bf16x8 Ah[2][NKT];
    #pragma unroll
    for (int i = 0; i < 2; ++i)
        #pragma unroll
        for (int kt = 0; kt < NKT; ++kt)
            Ah[i][kt] = *(const bf16x8*)(Abase + i * 16 * K_PAD + kt * BK);

    float rowp[2][4] = {};   // persistent across all col-tiles

    // ---- 2-phase pipeline: stage next tile, compute current, one barrier
    STAGE(0, colChunk);                  // prologue: tile 0 -> Bs[0]
    __syncthreads();                     // also covers colAcc zeroing

    #pragma unroll 1
    for (int ct = 0; ct < CTILES; ++ct) {
        if (ct + 1 < CTILES)
            STAGE((ct + 1) & 1, colChunk + (ct + 1) * 64);
        COMPUTE(ct & 1, colChunk + ct * 64);
        __syncthreads();                 // drains stage loads (long done) only
    }

    // ---- epilogue: all global atomics batched here, fire-and-forget ----
    // row sums: reduce across the 16 lanes of each quad (they hold cols)
    #pragma unroll
    for (int i = 0; i < 2; ++i) {
        #pragma unroll
        for (int reg = 0; reg < 4; ++reg) {
            float v = rowp[i][reg];
            v += __shfl_xor(v, 1);
            v += __shfl_xor(v, 2);
            v += __shfl_xor(v, 4);
            v += __shfl_xor(v, 8);
            if (l16 == 0)
                atomicAdd(&row_sum[rowBase + i * 16 + quad * 4 + reg], v);
        }
    }
    // col sums: one atomic per col per block, interleaved [col][4 reps];
    // last loop barrier already ordered all waves' ds_adds before here...
    // except wave skew after final barrier: colAcc reads need all ds_adds.
    // The final __syncthreads() in the loop IS after the last COMPUTE, so
    // all ds_adds are complete and visible. Safe to read.
    const int rep = strip & 3;
    for (int c = t; c < 512; c += 256)
        atomicAdd(&col_part[(colChunk + c) * 4 + rep], colAcc[c]);
}

// ---------------------------------------------------------------------------
// Kernel 3: loss = mean_b( 0.5*(ln rs[b] + ln cs[b]) - diag[b] ),
// cs[b] = sum of the 4 interleaved replicas (one dwordx4 read).
// ---------------------------------------------------------------------------
__global__ __launch_bounds__(1024) void finalize_kernel(
    const float* __restrict__ rs, const float* __restrict__ cp,
    const float* __restrict__ dg, float* __restrict__ out)
{
    __shared__ float part[16];
    int t = threadIdx.x;
    float a = 0.f;
    const float LN2_HALF = 0.34657359027997264f;  // 0.5 * ln2
    for (int b = t; b < BDIM; b += 1024) {
        f32x4 cv = *(const f32x4*)&cp[b * 4];
        float cs = cv[0] + cv[1] + cv[2] + cv[3];
        a += LN2_HALF * (fast_log2(rs[b]) + fast_log2(cs)) - dg[b];
    }
    #pragma unroll
    for (int m = 1; m < 64; m <<= 1) a += __shfl_xor(a, m);
    if ((t & 63) == 0) part[t >> 6] = a;
    __syncthreads();
    if (t < 16) {
        float v = part[t];
        #pragma unroll
        for (int m = 1; m < 16; m <<= 1) v += __shfl_xor(v, m);
        if (t == 0) out[0] = v * (1.0f / (float)BDIM);
    }
}

// ---------------------------------------------------------------------------
extern "C" void kernel_launch(void* const* d_in, const int* in_sizes, int n_in,
                              void* d_out, int out_size, void* d_ws, size_t ws_size,
                              hipStream_t stream)
{
    const float* z1 = (const float*)d_in[0];
    const float* z2 = (const float*)d_in[1];
    float* out = (float*)d_out;

    char* ws = (char*)d_ws;
    unsigned short* A  = (unsigned short*)(ws + OFF_A);
    unsigned short* B  = (unsigned short*)(ws + OFF_B);
    float* row_sum     = (float*)(ws + OFF_RS);
    float* col_part    = (float*)(ws + OFF_CP);
    float* diag        = (float*)(ws + OFF_DG);

    convert_kernel<<<(BDIM * (K_PAD / 8) + 255) / 256, 256, 0, stream>>>(
        z1, z2, A, B, row_sum /* rs + interleaved col sums contiguous */);

    gemm_epilogue_kernel<<<1024, 256, 0, stream>>>(
        A, B, row_sum, col_part, diag);

    finalize_kernel<<<1, 1024, 0, stream>>>(row_sum, col_part, diag, out);
}

// Round 7
// 117.578 us; speedup vs baseline: 1.0076x; 1.0076x over previous
//
#include <hip/hip_runtime.h>
#include <math.h>

// ---------------------------------------------------------------------------
// HyperbolicInfoNCE on MI355X — Round 13: tail-free grid (512 = 2 blocks/CU).
//
// R12 post-mortem: OccupancyPercent 22.8% = 1.8 waves/SIMD achieved vs
// capacity 3. Grid 1024 at 3 blocks/CU = 768-block generation + 256-block
// TAIL at 1 block/CU (no latency hiding) -> ~40% of wall. Every in-loop
// micro-fix since R6 was fighting this tail. Also R12's col drain used
// [col][4] interleave = all 4 replicas in ONE cacheline -> 64 blocks
// hammering the same line (regression 48.3->55.4).
//
// R13: grid = 512 blocks (8 chunks x 64 strips), block = 128 rows x 1024
// cols (16 tiles of 64) -> exactly 2 blocks/CU, all resident from t=0, no
// tail. Per-SIMD trans demand (the floor) = 20.5us; 2 waves at ~65% trans
// duty oversubscribe the trans pipe 1.3x -> trans-bound wall ~28-35us.
// Col drain to SEPARATED replicas col_part[rep*BDIM+col]. Convert float4-
// granular (16B lane stride loads, 8B stores).
// ---------------------------------------------------------------------------

#define BDIM   8192
#define K_IN   129
#define K_PAD  160      // 5 * 32
#define BK     32
#define NKT    5        // k-tiles of 32
#define CTILES 16       // 64-col tiles per block (128 rows x 1024 cols)

typedef __bf16  bf16x8 __attribute__((ext_vector_type(8)));
typedef float   f32x4  __attribute__((ext_vector_type(4)));
typedef unsigned short u16x4 __attribute__((ext_vector_type(4)));

// ws layout (bytes)
#define OFF_A    0u
#define OFF_B    (BDIM * K_PAD * 2u)                  // 2,621,440
#define OFF_RS   (2u * BDIM * K_PAD * 2u)             // 5,242,880
#define OFF_CP   (OFF_RS + BDIM * 4u)                 // 4 separated col replicas
#define OFF_DG   (OFF_CP + 4u * BDIM * 4u)

// ---- hardware transcendentals (v_sqrt_f32 / v_log_f32 / v_exp_f32) ----
__device__ __forceinline__ float fast_sqrt(float x) {
#if __has_builtin(__builtin_amdgcn_sqrtf)
    return __builtin_amdgcn_sqrtf(x);
#else
    return sqrtf(x);
#endif
}
__device__ __forceinline__ float fast_log2(float x) {
#if __has_builtin(__builtin_amdgcn_logf)
    return __builtin_amdgcn_logf(x);       // log base 2
#else
    return __log2f(x);
#endif
}
__device__ __forceinline__ float fast_exp2(float x) {
#if __has_builtin(__builtin_amdgcn_exp2f)
    return __builtin_amdgcn_exp2f(x);      // 2^x
#else
    extern "C" __device__ float __ocml_native_exp2_f32(float);
    return __ocml_native_exp2_f32(x);
#endif
}

__device__ __forceinline__ unsigned short f2bf_rne(float f) {
    unsigned int u = __float_as_uint(f);
    u += 0x7FFFu + ((u >> 16) & 1u);   // round-to-nearest-even
    return (unsigned short)(u >> 16);
}

// ---------------------------------------------------------------------------
// Kernel 1: fp32 -> bf16, float4-granular: thread handles 4 consecutive
// elements (16B lane stride on loads, 8B u16x4 stores). K zero-padded
// 129->160, Lorentz metric folded into A (negate col 0). Also zeroes
// row_sum + 4 col replicas. Grid: BDIM*40 threads = 1280 blocks.
// ---------------------------------------------------------------------------
__global__ __launch_bounds__(256) void convert_kernel(
    const float* __restrict__ z1, const float* __restrict__ z2,
    unsigned short* __restrict__ A, unsigned short* __restrict__ B,
    float* __restrict__ rs_cp)
{
    int v = blockIdx.x * 256 + threadIdx.x;
    if (v < 5 * BDIM) rs_cp[v] = 0.f;          // rs (8192) + cp (4*8192)
    if (v >= BDIM * (K_PAD / 4)) return;
    int r  = v / (K_PAD / 4);
    int c4 = (v - r * (K_PAD / 4)) * 4;
    u16x4 a, b;
    #pragma unroll
    for (int i = 0; i < 4; ++i) {
        int c = c4 + i;
        float va = 0.f, vb = 0.f;
        if (c < K_IN) {
            va = z1[r * K_IN + c];
            vb = z2[r * K_IN + c];
            if (c == 0) va = -va;              // Lorentz metric on coord 0
        }
        a[i] = f2bf_rne(va);
        b[i] = f2bf_rne(vb);
    }
    *(u16x4*)(A + r * K_PAD + c4) = a;
    *(u16x4*)(B + r * K_PAD + c4) = b;
}

// ---------------------------------------------------------------------------
// Kernel 2: strip-GEMM with fused acosh/exp epilogue; B staged through a
// double-buffered LDS pipeline (global_load_lds); col sums in LDS.
//   grid = 512: bid = chunk*64 + strip  (8 chunks x 64 strips; consecutive
//   blocks share one 320KB B-chunk in L2)
//   block: rows [strip*128, +128) x cols [chunk*1024, +1024), 16 tiles
//   wave w (0..3): rows [strip*128 + w*32, +32)
//   fragment layouts (guide-verified, m89/m91):
//     A/B operand: elem [m=lane&15][k=(lane>>4)*8 + j]
//     C/D:         elem [row=(lane>>4)*4 + reg][col=lane&15]
// ---------------------------------------------------------------------------

// Stage one 64-col B-tile (20KB contiguous global chunk) into Bs[bufidx].
// Each wave issues 5 async 1KB copies; LDS dest wave-uniform + lane*16 (m104).
#define STAGE(bufidx, cb)                                                     \
    {                                                                         \
        const char* _gp = (const char*)(B + (size_t)(cb) * K_PAD)             \
                          + wave * 5120 + lane * 16;                          \
        unsigned short* _lp = &Bs[bufidx][wave * 2560];                       \
        _Pragma("unroll")                                                     \
        for (int _i = 0; _i < 5; ++_i)                                        \
            __builtin_amdgcn_global_load_lds(                                 \
                (const __attribute__((address_space(1))) void*)               \
                    (_gp + _i * 1024),                                        \
                (__attribute__((address_space(3))) void*)(_lp + _i * 512),    \
                16, 0, 0);                                                    \
    }

// MFMA + fused epilogue for one 32x64 wave-tile read from Bs[bufidx].
// Col partials -> LDS colAcc (ds_add_f32); NO global atomics in the loop.
#define COMPUTE(bufidx, cb)                                                   \
    {                                                                         \
        const int colBase = (cb);                                             \
        const unsigned short* _Bt = &Bs[bufidx][0];                           \
        f32x4 acc[2][4] = {};                                                 \
        _Pragma("unroll")                                                     \
        for (int kt = 0; kt < NKT; ++kt) {                                    \
            bf16x8 bfr[4];                                                    \
            _Pragma("unroll")                                                 \
            for (int j = 0; j < 4; ++j)                                       \
                bfr[j] = *(const bf16x8*)                                     \
                    &_Bt[(l16 + j * 16) * K_PAD + quad * 8 + kt * BK];        \
            _Pragma("unroll")                                                 \
            for (int i = 0; i < 2; ++i)                                       \
                _Pragma("unroll")                                             \
                for (int j = 0; j < 4; ++j)                                   \
                    acc[i][j] = __builtin_amdgcn_mfma_f32_16x16x32_bf16(      \
                        Ah[i][kt], bfr[j], acc[i][j], 0, 0, 0);               \
        }                                                                     \
        const bool diagTile = (colBase == (rowBase & ~63));                   \
        const int  dj       = (rowBase >> 4) & 2;                             \
        float colp[4] = {0.f, 0.f, 0.f, 0.f};                                 \
        _Pragma("unroll")                                                     \
        for (int i = 0; i < 2; ++i) {                                         \
            _Pragma("unroll")                                                 \
            for (int j = 0; j < 4; ++j) {                                     \
                _Pragma("unroll")                                             \
                for (int reg = 0; reg < 4; ++reg) {                           \
                    float inner = acc[i][j][reg];                             \
                    float x = fmaxf(-inner, 1.000001f);                       \
                    float s = fast_sqrt(__builtin_fmaf(x, x, -1.0f));         \
                    float l2u = fast_log2(x + s);                             \
                    float e = fast_exp2(-14.285714285714286f * l2u);          \
                    rowp[i][reg] += e;                                        \
                    colp[j]      += e;                                        \
                    if (diagTile && (j - i) == dj && (quad * 4 + reg) == l16){\
                        int R = rowBase + i * 16 + quad * 4 + reg;            \
                        diag[R] = -9.902102579427789f * l2u;                  \
                    }                                                         \
                }                                                             \
            }                                                                 \
        }                                                                     \
        _Pragma("unroll")                                                     \
        for (int j = 0; j < 4; ++j) {                                         \
            float v = colp[j];                                                \
            v += __shfl_xor(v, 16);                                           \
            v += __shfl_xor(v, 32);                                           \
            if (quad == 0)                                                    \
                atomicAdd(&colAcc[(colBase - colChunk) + j * 16 + l16], v);   \
        }                                                                     \
    }

__global__ __launch_bounds__(256, 3) void gemm_epilogue_kernel(
    const unsigned short* __restrict__ A, const unsigned short* __restrict__ B,
    float* __restrict__ row_sum, float* __restrict__ col_part,
    float* __restrict__ diag)
{
    const int t    = threadIdx.x;
    const int lane = t & 63;
    const int wave = t >> 6;
    const int quad = lane >> 4;
    const int l16  = lane & 15;

    const int strip = blockIdx.x & 63;
    const int chunk = blockIdx.x >> 6;                // 0..7
    const int rowBase  = strip * 128 + wave * 32;     // wave's first row
    const int colChunk = chunk * 1024;                // block's first col

    const unsigned short* Abase = A + (rowBase + l16) * K_PAD + quad * 8;

    // B-tile double buffer (linear copy of contiguous global chunk) + block
    // col accumulator (LDS atomics in-loop, drained to global ONCE at end).
    __shared__ __align__(16) unsigned short Bs[2][64 * K_PAD];
    __shared__ float colAcc[1024];

    for (int c = t; c < 1024; c += 256) colAcc[c] = 0.f;

    // ---- hoist the entire A operand for this wave: 2 row-frags x 5 k-tiles
    bf16x8 Ah[2][NKT];
    #pragma unroll
    for (int i = 0; i < 2; ++i)
        #pragma unroll
        for (int kt = 0; kt < NKT; ++kt)
            Ah[i][kt] = *(const bf16x8*)(Abase + i * 16 * K_PAD + kt * BK);

    float rowp[2][4] = {};   // persistent across all col-tiles

    // ---- 2-phase pipeline: stage next tile, compute current, one barrier
    STAGE(0, colChunk);                  // prologue: tile 0 -> Bs[0]
    __syncthreads();                     // also covers colAcc zeroing

    #pragma unroll 1
    for (int ct = 0; ct < CTILES; ++ct) {
        if (ct + 1 < CTILES)
            STAGE((ct + 1) & 1, colChunk + (ct + 1) * 64);
        COMPUTE(ct & 1, colChunk + ct * 64);
        __syncthreads();                 // drains stage loads (done under compute)
    }

    // ---- epilogue: all global atomics batched here, fire-and-forget ----
    // row sums: reduce across the 16 lanes of each quad (they hold cols)
    #pragma unroll
    for (int i = 0; i < 2; ++i) {
        #pragma unroll
        for (int reg = 0; reg < 4; ++reg) {
            float v = rowp[i][reg];
            v += __shfl_xor(v, 1);
            v += __shfl_xor(v, 2);
            v += __shfl_xor(v, 4);
            v += __shfl_xor(v, 8);
            if (l16 == 0)
                atomicAdd(&row_sum[rowBase + i * 16 + quad * 4 + reg], v);
        }
    }
    // col sums: one atomic per col per block, to SEPARATED replica arrays
    // (R12's [col][4] interleave put all replicas in one cacheline — bug).
    // All ds_adds are ordered before here by the last loop __syncthreads().
    const int rep = strip & 3;
    for (int c = t; c < 1024; c += 256)
        atomicAdd(&col_part[rep * BDIM + colChunk + c], colAcc[c]);
}

// ---------------------------------------------------------------------------
// Kernel 3: loss = mean_b( 0.5*(ln rs[b] + ln cs[b]) - diag[b] ),
// cs[b] = sum of 4 separated replicas.
// ---------------------------------------------------------------------------
__global__ __launch_bounds__(1024) void finalize_kernel(
    const float* __restrict__ rs, const float* __restrict__ cp,
    const float* __restrict__ dg, float* __restrict__ out)
{
    __shared__ float part[16];
    int t = threadIdx.x;
    float a = 0.f;
    const float LN2_HALF = 0.34657359027997264f;  // 0.5 * ln2
    for (int b = t; b < BDIM; b += 1024) {
        float cs = cp[b] + cp[b + BDIM] + cp[b + 2 * BDIM] + cp[b + 3 * BDIM];
        a += LN2_HALF * (fast_log2(rs[b]) + fast_log2(cs)) - dg[b];
    }
    #pragma unroll
    for (int m = 1; m < 64; m <<= 1) a += __shfl_xor(a, m);
    if ((t & 63) == 0) part[t >> 6] = a;
    __syncthreads();
    if (t < 16) {
        float v = part[t];
        #pragma unroll
        for (int m = 1; m < 16; m <<= 1) v += __shfl_xor(v, m);
        if (t == 0) out[0] = v * (1.0f / (float)BDIM);
    }
}

// ---------------------------------------------------------------------------
extern "C" void kernel_launch(void* const* d_in, const int* in_sizes, int n_in,
                              void* d_out, int out_size, void* d_ws, size_t ws_size,
                              hipStream_t stream)
{
    const float* z1 = (const float*)d_in[0];
    const float* z2 = (const float*)d_in[1];
    float* out = (float*)d_out;

    char* ws = (char*)d_ws;
    unsigned short* A  = (unsigned short*)(ws + OFF_A);
    unsigned short* B  = (unsigned short*)(ws + OFF_B);
    float* row_sum     = (float*)(ws + OFF_RS);
    float* col_part    = (float*)(ws + OFF_CP);
    float* diag        = (float*)(ws + OFF_DG);

    convert_kernel<<<(BDIM * (K_PAD / 4) + 255) / 256, 256, 0, stream>>>(
        z1, z2, A, B, row_sum /* rs + 4 separated col replicas contiguous */);

    gemm_epilogue_kernel<<<512, 256, 0, stream>>>(
        A, B, row_sum, col_part, diag);

    finalize_kernel<<<1, 1024, 0, stream>>>(row_sum, col_part, diag, out);
}

// Round 8
// 108.786 us; speedup vs baseline: 1.0890x; 1.0808x over previous
//
#include <hip/hip_runtime.h>
#include <math.h>

// ---------------------------------------------------------------------------
// HyperbolicInfoNCE on MI355X — Round 14: 4 blocks/CU, tail-free grid 1024.
//
// R13 post-mortem: grid 512 (2 blocks/CU "tail-free") REGRESSED (57.2us,
// occupancy 18.6%). Across all rounds: VALUBusy*dur ~= 25us and
// MfmaUtil*dur ~= 8us are INVARIANT; dur is a monotone function of achieved
// occupancy (18.6%->57.2, 22.8%->55.4, 30.8%->48.3). The kernel is pure
// latency-bound; the only lever is resident waves. R13 cut residency in
// half — wrong sign. The right geometry: grid 1024 = EXACTLY 4 blocks/CU
// (tail-free AND denser than R10's 3/CU main phase).
//
// R14 = R10's gemm + launch_bounds(256,4) + colAcc dropped so LDS = 40960B
// exactly (160KB/4). Unified reg usage ~100 <= 128 cap. In-loop global col
// atomics restored (R12 ablation exonerated them). Flat 16 waves/CU = 50%
// occupancy ceiling; 4 waves/SIMD oversubscribe the trans pipe -> wall
// approaches the 20.5us/SIMD transcendental floor.
// ---------------------------------------------------------------------------

#define BDIM   8192
#define K_IN   129
#define K_PAD  160      // 5 * 32
#define BK     32
#define NKT    5        // k-tiles of 32
#define CTILES 8        // 64-col tiles per block (128 rows x 512 cols)

typedef __bf16  bf16x8 __attribute__((ext_vector_type(8)));
typedef float   f32x4  __attribute__((ext_vector_type(4)));
typedef unsigned short u16x4 __attribute__((ext_vector_type(4)));

// ws layout (bytes)
#define OFF_A    0u
#define OFF_B    (BDIM * K_PAD * 2u)                  // 2,621,440
#define OFF_RS   (2u * BDIM * K_PAD * 2u)             // 5,242,880
#define OFF_CP   (OFF_RS + BDIM * 4u)                 // 4 separated col replicas
#define OFF_DG   (OFF_CP + 4u * BDIM * 4u)

// ---- hardware transcendentals (v_sqrt_f32 / v_log_f32 / v_exp_f32) ----
__device__ __forceinline__ float fast_sqrt(float x) {
#if __has_builtin(__builtin_amdgcn_sqrtf)
    return __builtin_amdgcn_sqrtf(x);
#else
    return sqrtf(x);
#endif
}
__device__ __forceinline__ float fast_log2(float x) {
#if __has_builtin(__builtin_amdgcn_logf)
    return __builtin_amdgcn_logf(x);       // log base 2
#else
    return __log2f(x);
#endif
}
__device__ __forceinline__ float fast_exp2(float x) {
#if __has_builtin(__builtin_amdgcn_exp2f)
    return __builtin_amdgcn_exp2f(x);      // 2^x
#else
    extern "C" __device__ float __ocml_native_exp2_f32(float);
    return __ocml_native_exp2_f32(x);
#endif
}

__device__ __forceinline__ unsigned short f2bf_rne(float f) {
    unsigned int u = __float_as_uint(f);
    u += 0x7FFFu + ((u >> 16) & 1u);   // round-to-nearest-even
    return (unsigned short)(u >> 16);
}

// ---------------------------------------------------------------------------
// Kernel 1: fp32 -> bf16, float4-granular: thread handles 4 consecutive
// elements (16B lane stride on loads, 8B u16x4 stores). K zero-padded
// 129->160, Lorentz metric folded into A (negate col 0). Also zeroes
// row_sum + 4 col replicas.
// ---------------------------------------------------------------------------
__global__ __launch_bounds__(256) void convert_kernel(
    const float* __restrict__ z1, const float* __restrict__ z2,
    unsigned short* __restrict__ A, unsigned short* __restrict__ B,
    float* __restrict__ rs_cp)
{
    int v = blockIdx.x * 256 + threadIdx.x;
    if (v < 5 * BDIM) rs_cp[v] = 0.f;          // rs (8192) + cp (4*8192)
    if (v >= BDIM * (K_PAD / 4)) return;
    int r  = v / (K_PAD / 4);
    int c4 = (v - r * (K_PAD / 4)) * 4;
    u16x4 a, b;
    #pragma unroll
    for (int i = 0; i < 4; ++i) {
        int c = c4 + i;
        float va = 0.f, vb = 0.f;
        if (c < K_IN) {
            va = z1[r * K_IN + c];
            vb = z2[r * K_IN + c];
            if (c == 0) va = -va;              // Lorentz metric on coord 0
        }
        a[i] = f2bf_rne(va);
        b[i] = f2bf_rne(vb);
    }
    *(u16x4*)(A + r * K_PAD + c4) = a;
    *(u16x4*)(B + r * K_PAD + c4) = b;
}

// ---------------------------------------------------------------------------
// Kernel 2: strip-GEMM with fused acosh/exp epilogue; B staged through a
// double-buffered LDS pipeline (global_load_lds).
//   grid = 1024: bid = chunk*64 + strip  (consecutive blocks share B-chunk)
//   block: rows [strip*128, +128) x cols [chunk*512, +512), 8 tiles of 64
//   wave w (0..3): rows [strip*128 + w*32, +32)
//   4 blocks/CU resident (LDS 40960 = 160KB/4, launch_bounds(256,4)).
//   fragment layouts (guide-verified, m89/m91):
//     A/B operand: elem [m=lane&15][k=(lane>>4)*8 + j]
//     C/D:         elem [row=(lane>>4)*4 + reg][col=lane&15]
// ---------------------------------------------------------------------------

// Stage one 64-col B-tile (20KB contiguous global chunk) into Bs[bufidx].
// Each wave issues 5 async 1KB copies; LDS dest wave-uniform + lane*16 (m104).
#define STAGE(bufidx, cb)                                                     \
    {                                                                         \
        const char* _gp = (const char*)(B + (size_t)(cb) * K_PAD)             \
                          + wave * 5120 + lane * 16;                          \
        unsigned short* _lp = &Bs[bufidx][wave * 2560];                       \
        _Pragma("unroll")                                                     \
        for (int _i = 0; _i < 5; ++_i)                                        \
            __builtin_amdgcn_global_load_lds(                                 \
                (const __attribute__((address_space(1))) void*)               \
                    (_gp + _i * 1024),                                        \
                (__attribute__((address_space(3))) void*)(_lp + _i * 512),    \
                16, 0, 0);                                                    \
    }

// MFMA + fused epilogue for one 32x64 wave-tile read from Bs[bufidx].
#define COMPUTE(bufidx, cb)                                                   \
    {                                                                         \
        const int colBase = (cb);                                             \
        const unsigned short* _Bt = &Bs[bufidx][0];                           \
        f32x4 acc[2][4] = {};                                                 \
        _Pragma("unroll")                                                     \
        for (int kt = 0; kt < NKT; ++kt) {                                    \
            bf16x8 bfr[4];                                                    \
            _Pragma("unroll")                                                 \
            for (int j = 0; j < 4; ++j)                                       \
                bfr[j] = *(const bf16x8*)                                     \
                    &_Bt[(l16 + j * 16) * K_PAD + quad * 8 + kt * BK];        \
            _Pragma("unroll")                                                 \
            for (int i = 0; i < 2; ++i)                                       \
                _Pragma("unroll")                                             \
                for (int j = 0; j < 4; ++j)                                   \
                    acc[i][j] = __builtin_amdgcn_mfma_f32_16x16x32_bf16(      \
                        Ah[i][kt], bfr[j], acc[i][j], 0, 0, 0);               \
        }                                                                     \
        const bool diagTile = (colBase == (rowBase & ~63));                   \
        const int  dj       = (rowBase >> 4) & 2;                             \
        float colp[4] = {0.f, 0.f, 0.f, 0.f};                                 \
        _Pragma("unroll")                                                     \
        for (int i = 0; i < 2; ++i) {                                         \
            _Pragma("unroll")                                                 \
            for (int j = 0; j < 4; ++j) {                                     \
                _Pragma("unroll")                                             \
                for (int reg = 0; reg < 4; ++reg) {                           \
                    float inner = acc[i][j][reg];                             \
                    float x = fmaxf(-inner, 1.000001f);                       \
                    float s = fast_sqrt(__builtin_fmaf(x, x, -1.0f));         \
                    float l2u = fast_log2(x + s);                             \
                    float e = fast_exp2(-14.285714285714286f * l2u);          \
                    rowp[i][reg] += e;                                        \
                    colp[j]      += e;                                        \
                    if (diagTile && (j - i) == dj && (quad * 4 + reg) == l16){\
                        int R = rowBase + i * 16 + quad * 4 + reg;            \
                        diag[R] = -9.902102579427789f * l2u;                  \
                    }                                                         \
                }                                                             \
            }                                                                 \
        }                                                                     \
        _Pragma("unroll")                                                     \
        for (int j = 0; j < 4; ++j) {                                         \
            float v = colp[j];                                                \
            v += __shfl_xor(v, 16);                                           \
            v += __shfl_xor(v, 32);                                           \
            if (quad == 0)                                                    \
                atomicAdd(&colRep[colBase + j * 16 + l16], v);                \
        }                                                                     \
    }

__global__ __launch_bounds__(256, 4) void gemm_epilogue_kernel(
    const unsigned short* __restrict__ A, const unsigned short* __restrict__ B,
    float* __restrict__ row_sum, float* __restrict__ col_part,
    float* __restrict__ diag)
{
    const int t    = threadIdx.x;
    const int lane = t & 63;
    const int wave = t >> 6;
    const int quad = lane >> 4;
    const int l16  = lane & 15;

    const int strip = blockIdx.x & 63;
    const int chunk = blockIdx.x >> 6;                // 0..15
    const int rowBase  = strip * 128 + wave * 32;     // wave's first row
    const int colChunk = chunk * 512;                 // block's first col

    const unsigned short* Abase = A + (rowBase + l16) * K_PAD + quad * 8;
    float* colRep = col_part + (strip & 3) * BDIM;    // contention / 4

    // B-tile double buffer: exactly 40960 B = 160KB / 4 blocks.
    __shared__ __align__(16) unsigned short Bs[2][64 * K_PAD];

    // ---- hoist the entire A operand for this wave: 2 row-frags x 5 k-tiles
    bf16x8 Ah[2][NKT];
    #pragma unroll
    for (int i = 0; i < 2; ++i)
        #pragma unroll
        for (int kt = 0; kt < NKT; ++kt)
            Ah[i][kt] = *(const bf16x8*)(Abase + i * 16 * K_PAD + kt * BK);

    float rowp[2][4] = {};   // persistent across all col-tiles

    // ---- 2-phase pipeline: stage next tile, compute current, one barrier
    STAGE(0, colChunk);                  // prologue: tile 0 -> Bs[0]
    __syncthreads();

    #pragma unroll 1
    for (int ct = 0; ct < CTILES; ++ct) {
        if (ct + 1 < CTILES)
            STAGE((ct + 1) & 1, colChunk + (ct + 1) * 64);
        COMPUTE(ct & 1, colChunk + ct * 64);
        __syncthreads();                 // drains stage loads (done under compute)
    }

    // row sums: accumulated over all 8 col-tiles; reduce across the 16
    // lanes of each quad (they hold the cols), one atomic per row
    #pragma unroll
    for (int i = 0; i < 2; ++i) {
        #pragma unroll
        for (int reg = 0; reg < 4; ++reg) {
            float v = rowp[i][reg];
            v += __shfl_xor(v, 1);
            v += __shfl_xor(v, 2);
            v += __shfl_xor(v, 4);
            v += __shfl_xor(v, 8);
            if (l16 == 0)
                atomicAdd(&row_sum[rowBase + i * 16 + quad * 4 + reg], v);
        }
    }
}

// ---------------------------------------------------------------------------
// Kernel 3: loss = mean_b( 0.5*(ln rs[b] + ln cs[b]) - diag[b] ),
// cs[b] = sum of 4 separated replicas.
// ---------------------------------------------------------------------------
__global__ __launch_bounds__(1024) void finalize_kernel(
    const float* __restrict__ rs, const float* __restrict__ cp,
    const float* __restrict__ dg, float* __restrict__ out)
{
    __shared__ float part[16];
    int t = threadIdx.x;
    float a = 0.f;
    const float LN2_HALF = 0.34657359027997264f;  // 0.5 * ln2
    for (int b = t; b < BDIM; b += 1024) {
        float cs = cp[b] + cp[b + BDIM] + cp[b + 2 * BDIM] + cp[b + 3 * BDIM];
        a += LN2_HALF * (fast_log2(rs[b]) + fast_log2(cs)) - dg[b];
    }
    #pragma unroll
    for (int m = 1; m < 64; m <<= 1) a += __shfl_xor(a, m);
    if ((t & 63) == 0) part[t >> 6] = a;
    __syncthreads();
    if (t < 16) {
        float v = part[t];
        #pragma unroll
        for (int m = 1; m < 16; m <<= 1) v += __shfl_xor(v, m);
        if (t == 0) out[0] = v * (1.0f / (float)BDIM);
    }
}

// ---------------------------------------------------------------------------
extern "C" void kernel_launch(void* const* d_in, const int* in_sizes, int n_in,
                              void* d_out, int out_size, void* d_ws, size_t ws_size,
                              hipStream_t stream)
{
    const float* z1 = (const float*)d_in[0];
    const float* z2 = (const float*)d_in[1];
    float* out = (float*)d_out;

    char* ws = (char*)d_ws;
    unsigned short* A  = (unsigned short*)(ws + OFF_A);
    unsigned short* B  = (unsigned short*)(ws + OFF_B);
    float* row_sum     = (float*)(ws + OFF_RS);
    float* col_part    = (float*)(ws + OFF_CP);
    float* diag        = (float*)(ws + OFF_DG);

    convert_kernel<<<(BDIM * (K_PAD / 4) + 255) / 256, 256, 0, stream>>>(
        z1, z2, A, B, row_sum /* rs + 4 separated col replicas contiguous */);

    gemm_epilogue_kernel<<<1024, 256, 0, stream>>>(
        A, B, row_sum, col_part, diag);

    finalize_kernel<<<1, 1024, 0, stream>>>(row_sum, col_part, diag, out);
}

// Round 9
// 108.707 us; speedup vs baseline: 1.0898x; 1.0007x over previous
//
#include <hip/hip_runtime.h>
#include <math.h>

// ---------------------------------------------------------------------------
// HyperbolicInfoNCE on MI355X — Round 15: 8-wave blocks, 16 waves/CU.
//
// R14 post-mortem: 4 x 40960B = exactly 163840B requires every byte of the
// 160KiB LDS -> 4th block never admitted (occupancy stuck 30.1%, dur 48.8).
// Exact-fit LDS geometry is fragile. The monotone occupancy->dur law
// (18.6%->57.2, 22.8%->55.4, 30.8%->48.3) says residency is the ONLY lever.
//
// R15: block = 512 threads (8 waves) sharing ONE 40KB B-buffer pair.
//   block covers 256 rows x 512 cols; wave w owns rows [.. + w*32, +32).
//   grid = 32 strips x 16 chunks = 512 = EXACTLY 2 blocks/CU, tail-free.
//   LDS 2 x 40960 = 81920B (78KB slack). 16 waves/CU = 4/SIMD; combined
//   regs ~100 <= 128 -> admissible (launch_bounds(512,4)).
// B-tile now amortized over 8 waves; stage = 20 x 1KB issues split 8 ways;
// col-atomic contention halved (8 contenders/replica).
// ---------------------------------------------------------------------------

#define BDIM   8192
#define K_IN   129
#define K_PAD  160      // 5 * 32
#define BK     32
#define NKT    5        // k-tiles of 32
#define CTILES 8        // 64-col tiles per block (256 rows x 512 cols)

typedef __bf16  bf16x8 __attribute__((ext_vector_type(8)));
typedef float   f32x4  __attribute__((ext_vector_type(4)));
typedef unsigned short u16x4 __attribute__((ext_vector_type(4)));

// ws layout (bytes)
#define OFF_A    0u
#define OFF_B    (BDIM * K_PAD * 2u)                  // 2,621,440
#define OFF_RS   (2u * BDIM * K_PAD * 2u)             // 5,242,880
#define OFF_CP   (OFF_RS + BDIM * 4u)                 // 4 separated col replicas
#define OFF_DG   (OFF_CP + 4u * BDIM * 4u)

// ---- hardware transcendentals (v_sqrt_f32 / v_log_f32 / v_exp_f32) ----
__device__ __forceinline__ float fast_sqrt(float x) {
#if __has_builtin(__builtin_amdgcn_sqrtf)
    return __builtin_amdgcn_sqrtf(x);
#else
    return sqrtf(x);
#endif
}
__device__ __forceinline__ float fast_log2(float x) {
#if __has_builtin(__builtin_amdgcn_logf)
    return __builtin_amdgcn_logf(x);       // log base 2
#else
    return __log2f(x);
#endif
}
__device__ __forceinline__ float fast_exp2(float x) {
#if __has_builtin(__builtin_amdgcn_exp2f)
    return __builtin_amdgcn_exp2f(x);      // 2^x
#else
    extern "C" __device__ float __ocml_native_exp2_f32(float);
    return __ocml_native_exp2_f32(x);
#endif
}

__device__ __forceinline__ unsigned short f2bf_rne(float f) {
    unsigned int u = __float_as_uint(f);
    u += 0x7FFFu + ((u >> 16) & 1u);   // round-to-nearest-even
    return (unsigned short)(u >> 16);
}

// ---------------------------------------------------------------------------
// Kernel 1: fp32 -> bf16, float4-granular: thread handles 4 consecutive
// elements. K zero-padded 129->160, Lorentz metric folded into A (negate
// col 0). Also zeroes row_sum + 4 col replicas.
// ---------------------------------------------------------------------------
__global__ __launch_bounds__(256) void convert_kernel(
    const float* __restrict__ z1, const float* __restrict__ z2,
    unsigned short* __restrict__ A, unsigned short* __restrict__ B,
    float* __restrict__ rs_cp)
{
    int v = blockIdx.x * 256 + threadIdx.x;
    if (v < 5 * BDIM) rs_cp[v] = 0.f;          // rs (8192) + cp (4*8192)
    if (v >= BDIM * (K_PAD / 4)) return;
    int r  = v / (K_PAD / 4);
    int c4 = (v - r * (K_PAD / 4)) * 4;
    u16x4 a, b;
    #pragma unroll
    for (int i = 0; i < 4; ++i) {
        int c = c4 + i;
        float va = 0.f, vb = 0.f;
        if (c < K_IN) {
            va = z1[r * K_IN + c];
            vb = z2[r * K_IN + c];
            if (c == 0) va = -va;              // Lorentz metric on coord 0
        }
        a[i] = f2bf_rne(va);
        b[i] = f2bf_rne(vb);
    }
    *(u16x4*)(A + r * K_PAD + c4) = a;
    *(u16x4*)(B + r * K_PAD + c4) = b;
}

// ---------------------------------------------------------------------------
// Kernel 2: strip-GEMM with fused acosh/exp epilogue; B staged through a
// double-buffered LDS pipeline (global_load_lds), 8 waves per block.
//   grid = 512: bid = chunk*32 + strip  (consecutive blocks share B-chunk)
//   block: rows [strip*256, +256) x cols [chunk*512, +512), 8 tiles of 64
//   wave w (0..7): rows [strip*256 + w*32, +32)
//   2 blocks/CU resident (LDS 81920B, launch_bounds(512,4)) = 16 waves/CU.
//   fragment layouts (guide-verified, m89/m91):
//     A/B operand: elem [m=lane&15][k=(lane>>4)*8 + j]
//     C/D:         elem [row=(lane>>4)*4 + reg][col=lane&15]
// ---------------------------------------------------------------------------

// Stage one 64-col B-tile (20KB contiguous global chunk) into Bs[bufidx]:
// 20 x 1KB issues split across 8 waves (waves 0-7: 2 each; waves 0-3: +1).
// LDS dest is wave-uniform; HW adds lane*16 (m104). Pure linear byte copy.
#define STAGE(bufidx, cb)                                                     \
    {                                                                         \
        const char* _gp = (const char*)(B + (size_t)(cb) * K_PAD)             \
                          + lane * 16;                                        \
        char* _lp = (char*)&Bs[bufidx][0];                                    \
        __builtin_amdgcn_global_load_lds(                                     \
            (const __attribute__((address_space(1))) void*)                   \
                (_gp + wave * 1024),                                          \
            (__attribute__((address_space(3))) void*)(_lp + wave * 1024),     \
            16, 0, 0);                                                        \
        __builtin_amdgcn_global_load_lds(                                     \
            (const __attribute__((address_space(1))) void*)                   \
                (_gp + (wave + 8) * 1024),                                    \
            (__attribute__((address_space(3))) void*)(_lp + (wave + 8) * 1024),\
            16, 0, 0);                                                        \
        if (wave < 4)                                                         \
            __builtin_amdgcn_global_load_lds(                                 \
                (const __attribute__((address_space(1))) void*)               \
                    (_gp + (wave + 16) * 1024),                               \
                (__attribute__((address_space(3))) void*)(_lp + (wave + 16) * 1024),\
                16, 0, 0);                                                    \
    }

// MFMA + fused epilogue for one 32x64 wave-tile read from Bs[bufidx].
#define COMPUTE(bufidx, cb)                                                   \
    {                                                                         \
        const int colBase = (cb);                                             \
        const unsigned short* _Bt = &Bs[bufidx][0];                           \
        f32x4 acc[2][4] = {};                                                 \
        _Pragma("unroll")                                                     \
        for (int kt = 0; kt < NKT; ++kt) {                                    \
            bf16x8 bfr[4];                                                    \
            _Pragma("unroll")                                                 \
            for (int j = 0; j < 4; ++j)                                       \
                bfr[j] = *(const bf16x8*)                                     \
                    &_Bt[(l16 + j * 16) * K_PAD + quad * 8 + kt * BK];        \
            _Pragma("unroll")                                                 \
            for (int i = 0; i < 2; ++i)                                       \
                _Pragma("unroll")                                             \
                for (int j = 0; j < 4; ++j)                                   \
                    acc[i][j] = __builtin_amdgcn_mfma_f32_16x16x32_bf16(      \
                        Ah[i][kt], bfr[j], acc[i][j], 0, 0, 0);               \
        }                                                                     \
        const bool diagTile = (colBase == (rowBase & ~63));                   \
        const int  dj       = (rowBase >> 4) & 2;                             \
        float colp[4] = {0.f, 0.f, 0.f, 0.f};                                 \
        _Pragma("unroll")                                                     \
        for (int i = 0; i < 2; ++i) {                                         \
            _Pragma("unroll")                                                 \
            for (int j = 0; j < 4; ++j) {                                     \
                _Pragma("unroll")                                             \
                for (int reg = 0; reg < 4; ++reg) {                           \
                    float inner = acc[i][j][reg];                             \
                    float x = fmaxf(-inner, 1.000001f);                       \
                    float s = fast_sqrt(__builtin_fmaf(x, x, -1.0f));         \
                    float l2u = fast_log2(x + s);                             \
                    float e = fast_exp2(-14.285714285714286f * l2u);          \
                    rowp[i][reg] += e;                                        \
                    colp[j]      += e;                                        \
                    if (diagTile && (j - i) == dj && (quad * 4 + reg) == l16){\
                        int R = rowBase + i * 16 + quad * 4 + reg;            \
                        diag[R] = -9.902102579427789f * l2u;                  \
                    }                                                         \
                }                                                             \
            }                                                                 \
        }                                                                     \
        _Pragma("unroll")                                                     \
        for (int j = 0; j < 4; ++j) {                                         \
            float v = colp[j];                                                \
            v += __shfl_xor(v, 16);                                           \
            v += __shfl_xor(v, 32);                                           \
            if (quad == 0)                                                    \
                atomicAdd(&colRep[colBase + j * 16 + l16], v);                \
        }                                                                     \
    }

__global__ __launch_bounds__(512, 4) void gemm_epilogue_kernel(
    const unsigned short* __restrict__ A, const unsigned short* __restrict__ B,
    float* __restrict__ row_sum, float* __restrict__ col_part,
    float* __restrict__ diag)
{
    const int t    = threadIdx.x;
    const int lane = t & 63;
    const int wave = t >> 6;                          // 0..7
    const int quad = lane >> 4;
    const int l16  = lane & 15;

    const int strip = blockIdx.x & 31;                // 0..31 (256-row strips)
    const int chunk = blockIdx.x >> 5;                // 0..15 (512-col chunks)
    const int rowBase  = strip * 256 + wave * 32;     // wave's first row
    const int colChunk = chunk * 512;                 // block's first col

    const unsigned short* Abase = A + (rowBase + l16) * K_PAD + quad * 8;
    float* colRep = col_part + (strip & 3) * BDIM;    // contention / 4

    // B-tile double buffer: 40960B total, shared by all 8 waves.
    __shared__ __align__(16) unsigned short Bs[2][64 * K_PAD];

    // ---- hoist the entire A operand for this wave: 2 row-frags x 5 k-tiles
    bf16x8 Ah[2][NKT];
    #pragma unroll
    for (int i = 0; i < 2; ++i)
        #pragma unroll
        for (int kt = 0; kt < NKT; ++kt)
            Ah[i][kt] = *(const bf16x8*)(Abase + i * 16 * K_PAD + kt * BK);

    float rowp[2][4] = {};   // persistent across all col-tiles

    // ---- 2-phase pipeline: stage next tile, compute current, one barrier
    STAGE(0, colChunk);                  // prologue: tile 0 -> Bs[0]
    __syncthreads();

    #pragma unroll 1
    for (int ct = 0; ct < CTILES; ++ct) {
        if (ct + 1 < CTILES)
            STAGE((ct + 1) & 1, colChunk + (ct + 1) * 64);
        COMPUTE(ct & 1, colChunk + ct * 64);
        __syncthreads();                 // drains stage loads (done under compute)
    }

    // row sums: accumulated over all 8 col-tiles; reduce across the 16
    // lanes of each quad (they hold the cols), one atomic per row
    #pragma unroll
    for (int i = 0; i < 2; ++i) {
        #pragma unroll
        for (int reg = 0; reg < 4; ++reg) {
            float v = rowp[i][reg];
            v += __shfl_xor(v, 1);
            v += __shfl_xor(v, 2);
            v += __shfl_xor(v, 4);
            v += __shfl_xor(v, 8);
            if (l16 == 0)
                atomicAdd(&row_sum[rowBase + i * 16 + quad * 4 + reg], v);
        }
    }
}

// ---------------------------------------------------------------------------
// Kernel 3: loss = mean_b( 0.5*(ln rs[b] + ln cs[b]) - diag[b] ),
// cs[b] = sum of 4 separated replicas.
// ---------------------------------------------------------------------------
__global__ __launch_bounds__(1024) void finalize_kernel(
    const float* __restrict__ rs, const float* __restrict__ cp,
    const float* __restrict__ dg, float* __restrict__ out)
{
    __shared__ float part[16];
    int t = threadIdx.x;
    float a = 0.f;
    const float LN2_HALF = 0.34657359027997264f;  // 0.5 * ln2
    for (int b = t; b < BDIM; b += 1024) {
        float cs = cp[b] + cp[b + BDIM] + cp[b + 2 * BDIM] + cp[b + 3 * BDIM];
        a += LN2_HALF * (fast_log2(rs[b]) + fast_log2(cs)) - dg[b];
    }
    #pragma unroll
    for (int m = 1; m < 64; m <<= 1) a += __shfl_xor(a, m);
    if ((t & 63) == 0) part[t >> 6] = a;
    __syncthreads();
    if (t < 16) {
        float v = part[t];
        #pragma unroll
        for (int m = 1; m < 16; m <<= 1) v += __shfl_xor(v, m);
        if (t == 0) out[0] = v * (1.0f / (float)BDIM);
    }
}

// ---------------------------------------------------------------------------
extern "C" void kernel_launch(void* const* d_in, const int* in_sizes, int n_in,
                              void* d_out, int out_size, void* d_ws, size_t ws_size,
                              hipStream_t stream)
{
    const float* z1 = (const float*)d_in[0];
    const float* z2 = (const float*)d_in[1];
    float* out = (float*)d_out;

    char* ws = (char*)d_ws;
    unsigned short* A  = (unsigned short*)(ws + OFF_A);
    unsigned short* B  = (unsigned short*)(ws + OFF_B);
    float* row_sum     = (float*)(ws + OFF_RS);
    float* col_part    = (float*)(ws + OFF_CP);
    float* diag        = (float*)(ws + OFF_DG);

    convert_kernel<<<(BDIM * (K_PAD / 4) + 255) / 256, 256, 0, stream>>>(
        z1, z2, A, B, row_sum /* rs + 4 separated col replicas contiguous */);

    gemm_epilogue_kernel<<<512, 512, 0, stream>>>(
        A, B, row_sum, col_part, diag);

    finalize_kernel<<<1, 1024, 0, stream>>>(row_sum, col_part, diag, out);
}